// Round 1
// baseline (435.444 us; speedup 1.0000x reference)
//
#include <hip/hip_runtime.h>
#include <hip/hip_bf16.h>
#include <hip/hip_fp16.h>

// LFM2 short-conv block, fp16-MFMA implementation (round 1: correctness + m97 GEMM structure).
//   X[8192,2048] @ W_in^T[2048,6144] -> BCx ; Bx=Bg*x ; causal depthwise conv L=3 ; y=Cg*conv ;
//   y @ W_out^T -> out (fp32)

typedef _Float16 f16x8 __attribute__((ext_vector_type(8)));
typedef float    f32x4 __attribute__((ext_vector_type(4)));

#define GLD_LDS16(gsrc, sdst) \
  __builtin_amdgcn_global_load_lds((const __attribute__((address_space(1))) void*)(gsrc), \
                                   (__attribute__((address_space(3))) void*)(sdst), 16, 0, 0)

// ---------------- fp32 -> fp16 convert (8 elems/thread) ----------------
__global__ __launch_bounds__(256) void cvt_f32_f16(const float* __restrict__ in,
                                                   _Float16* __restrict__ out, int n) {
  int i = blockIdx.x * 256 + threadIdx.x;
  int base = i * 8;
  if (base >= n) return;
  const float4* p = reinterpret_cast<const float4*>(in) + i * 2;
  float4 a = p[0], b = p[1];
  f16x8 o;
  o[0] = (_Float16)a.x; o[1] = (_Float16)a.y; o[2] = (_Float16)a.z; o[3] = (_Float16)a.w;
  o[4] = (_Float16)b.x; o[5] = (_Float16)b.y; o[6] = (_Float16)b.z; o[7] = (_Float16)b.w;
  *reinterpret_cast<f16x8*>(out + base) = o;
}

// ---------------- NT GEMM: A[M,K] * B[N,K]^T -> C[M,N]  (fp16 in, fp32 acc) ----------------
// 128x128 tile, BK=32, 256 threads = 4 waves in 2x2, each wave 64x64 = 4x4 mfma_16x16x32 frags.
template <typename CT>
__global__ __launch_bounds__(256) void gemm_nt_f16(const _Float16* __restrict__ A,
                                                   const _Float16* __restrict__ B,
                                                   CT* __restrict__ C,
                                                   int M, int N, int K) {
  __shared__ _Float16 As[128 * 32];  // 8 KB, linear row-major [row][k]
  __shared__ _Float16 Bs[128 * 32];

  const int tid  = threadIdx.x;
  const int lane = tid & 63;
  const int wave = tid >> 6;
  const int wr   = wave >> 1;       // wave row (0..1)
  const int wc   = wave & 1;        // wave col (0..1)
  const int bm   = blockIdx.y * 128;
  const int bn   = blockIdx.x * 128;

  // staging: each global_load_lds inst covers 64 rows x 32 cols (256 lanes x 8 fp16)
  const _Float16* aS = A + (size_t)(bm + (tid >> 2)) * K + (tid & 3) * 8;
  const _Float16* bS = B + (size_t)(bn + (tid >> 2)) * K + (tid & 3) * 8;
  _Float16* sA = As + tid * 8;      // linear dest: base + lane*16B per wave
  _Float16* sB = Bs + tid * 8;
  const size_t rowskip = (size_t)64 * K;

  f32x4 acc[4][4] = {};

  const int arow = wr * 64 + (lane & 15);
  const int brow = wc * 64 + (lane & 15);
  const int kofs = (lane >> 4) * 8;

  const int nk = K >> 5;
  for (int kt = 0; kt < nk; ++kt) {
    __syncthreads();                       // previous compute done before overwrite
    GLD_LDS16(aS, sA);
    GLD_LDS16(aS + rowskip, sA + 2048);
    GLD_LDS16(bS, sB);
    GLD_LDS16(bS + rowskip, sB + 2048);
    aS += 32; bS += 32;
    __syncthreads();                       // drains vmcnt -> tiles ready
    f16x8 af[4], bf[4];
#pragma unroll
    for (int f = 0; f < 4; ++f)
      af[f] = *reinterpret_cast<const f16x8*>(As + (arow + f * 16) * 32 + kofs);
#pragma unroll
    for (int f = 0; f < 4; ++f)
      bf[f] = *reinterpret_cast<const f16x8*>(Bs + (brow + f * 16) * 32 + kofs);
#pragma unroll
    for (int i = 0; i < 4; ++i)
#pragma unroll
      for (int j = 0; j < 4; ++j)
        acc[i][j] = __builtin_amdgcn_mfma_f32_16x16x32_f16(af[i], bf[j], acc[i][j], 0, 0, 0);
  }

  // epilogue: D row = (lane>>4)*4 + reg, col = lane&15  [guide §3, m89/m91-verified]
  const int rbase = bm + wr * 64 + ((lane >> 4) << 2);
  const int cbase = bn + wc * 64 + (lane & 15);
#pragma unroll
  for (int i = 0; i < 4; ++i) {
#pragma unroll
    for (int j = 0; j < 4; ++j) {
      const int r0 = rbase + i * 16;
      const int c  = cbase + j * 16;
#pragma unroll
      for (int reg = 0; reg < 4; ++reg)
        C[(size_t)(r0 + reg) * N + c] = (CT)acc[i][j][reg];
    }
  }
}

// ---------------- conv + gating: y = Cg * causal_conv3(Bg * x) ----------------
// BCx[8192,6144] fp16 (cols: 0..2047 Bg, 2048..4095 Cg, 4096..6143 x) -> Y[8192,2048] fp16
// thread: 8 channels x 8 rows; blockIdx.x = row strip (8 rows), threadIdx.x = channel group.
__global__ __launch_bounds__(256) void conv_gate(const _Float16* __restrict__ BCx,
                                                 const float* __restrict__ Wc,   // [2048,1,3]
                                                 _Float16* __restrict__ Y) {
  const int h0 = threadIdx.x * 8;
  const int r0 = blockIdx.x * 8;
  const int s0 = r0 & 4095;          // position within batch (strips never cross batch)

  float w0[8], w1[8], w2[8];
#pragma unroll
  for (int j = 0; j < 8; ++j) {
    w0[j] = Wc[(h0 + j) * 3 + 0];    // multiplies Bx[s-2]
    w1[j] = Wc[(h0 + j) * 3 + 1];    // Bx[s-1]
    w2[j] = Wc[(h0 + j) * 3 + 2];    // Bx[s]
  }

  float bxm2[8] = {}, bxm1[8] = {};
  if (s0 != 0) {                     // s0 >= 8: both history rows exist in-batch
    const _Float16* pm2 = BCx + (size_t)(r0 - 2) * 6144 + h0;
    const _Float16* pm1 = BCx + (size_t)(r0 - 1) * 6144 + h0;
    f16x8 bg2 = *reinterpret_cast<const f16x8*>(pm2);
    f16x8 xx2 = *reinterpret_cast<const f16x8*>(pm2 + 4096);
    f16x8 bg1 = *reinterpret_cast<const f16x8*>(pm1);
    f16x8 xx1 = *reinterpret_cast<const f16x8*>(pm1 + 4096);
#pragma unroll
    for (int j = 0; j < 8; ++j) {
      bxm2[j] = (float)bg2[j] * (float)xx2[j];
      bxm1[j] = (float)bg1[j] * (float)xx1[j];
    }
  }

  for (int i = 0; i < 8; ++i) {
    const _Float16* pr = BCx + (size_t)(r0 + i) * 6144 + h0;
    f16x8 bg = *reinterpret_cast<const f16x8*>(pr);
    f16x8 cg = *reinterpret_cast<const f16x8*>(pr + 2048);
    f16x8 xx = *reinterpret_cast<const f16x8*>(pr + 4096);
    f16x8 o;
#pragma unroll
    for (int j = 0; j < 8; ++j) {
      float bx   = (float)bg[j] * (float)xx[j];
      float conv = w0[j] * bxm2[j] + w1[j] * bxm1[j] + w2[j] * bx;
      o[j] = (_Float16)((float)cg[j] * conv);
      bxm2[j] = bxm1[j];
      bxm1[j] = bx;
    }
    *reinterpret_cast<f16x8*>(Y + (size_t)(r0 + i) * 2048 + h0) = o;
  }
}

// ---------------- launcher ----------------
extern "C" void kernel_launch(void* const* d_in, const int* in_sizes, int n_in,
                              void* d_out, int out_size, void* d_ws, size_t ws_size,
                              hipStream_t stream) {
  const float* X  = (const float*)d_in[0];  // [2,4096,2048]
  const float* Wi = (const float*)d_in[1];  // [6144,2048]
  const float* Wc = (const float*)d_in[2];  // [2048,1,3]
  const float* Wo = (const float*)d_in[3];  // [2048,2048]
  float* out = (float*)d_out;               // [2,4096,2048] fp32

  // workspace layout (192 MiB total)
  char* ws = (char*)d_ws;
  _Float16* Xh   = (_Float16*)(ws);                    // 33,554,432 B
  _Float16* Wih  = (_Float16*)(ws + 33554432);         // 25,165,824 B
  _Float16* Woh  = (_Float16*)(ws + 58720256);         //  8,388,608 B
  _Float16* BCxh = (_Float16*)(ws + 67108864);         // 100,663,296 B
  _Float16* Yh   = (_Float16*)(ws + 167772160);        // 33,554,432 B -> total 201,326,592 B
  (void)ws_size; (void)in_sizes; (void)n_in; (void)out_size;

  // fp32 -> fp16 converts
  cvt_f32_f16<<<dim3(16777216 / 2048), 256, 0, stream>>>(X,  Xh,  16777216);
  cvt_f32_f16<<<dim3(12582912 / 2048), 256, 0, stream>>>(Wi, Wih, 12582912);
  cvt_f32_f16<<<dim3( 4194304 / 2048), 256, 0, stream>>>(Wo, Woh,  4194304);

  // in_proj: [8192,2048] x [6144,2048]^T -> BCx fp16
  gemm_nt_f16<_Float16><<<dim3(48, 64), 256, 0, stream>>>(Xh, Wih, BCxh, 8192, 6144, 2048);

  // gating + causal depthwise conv -> y fp16
  conv_gate<<<dim3(1024), 256, 0, stream>>>(BCxh, Wc, Yh);

  // out_proj: [8192,2048] x [2048,2048]^T -> out fp32
  gemm_nt_f16<float><<<dim3(16, 64), 256, 0, stream>>>(Yh, Woh, out, 8192, 2048, 2048);
}

// Round 3
// 348.886 us; speedup vs baseline: 1.2481x; 1.2481x over previous
//
#include <hip/hip_runtime.h>
#include <hip/hip_fp16.h>

// LFM2 short-conv block. Round 3: 256x256 8-phase GEMM (static 128KB LDS) for in_proj,
// round-1 128x128 GEMM for out_proj (bisect), fp16 MFMA throughout.

typedef _Float16 f16x8 __attribute__((ext_vector_type(8)));
typedef float    f32x4 __attribute__((ext_vector_type(4)));

#define GLD_LDS16(gsrc, sdst) \
  __builtin_amdgcn_global_load_lds((const __attribute__((address_space(1))) void*)(gsrc), \
                                   (__attribute__((address_space(3))) void*)(sdst), 16, 0, 0)

#define VMCNT4 asm volatile("s_waitcnt vmcnt(4)" ::: "memory")
#define VMCNT0 asm volatile("s_waitcnt vmcnt(0)" ::: "memory")
#define LGKM0  asm volatile("s_waitcnt lgkmcnt(0)" ::: "memory")
#define BAR    __builtin_amdgcn_s_barrier()

// ---------------- fp32 -> fp16 convert (8 elems/thread) ----------------
__global__ __launch_bounds__(256) void cvt_f32_f16(const float* __restrict__ in,
                                                   _Float16* __restrict__ out, int n) {
  int i = blockIdx.x * 256 + threadIdx.x;
  int base = i * 8;
  if (base >= n) return;
  const float4* p = reinterpret_cast<const float4*>(in) + i * 2;
  float4 a = p[0], b = p[1];
  f16x8 o;
  o[0] = (_Float16)a.x; o[1] = (_Float16)a.y; o[2] = (_Float16)a.z; o[3] = (_Float16)a.w;
  o[4] = (_Float16)b.x; o[5] = (_Float16)b.y; o[6] = (_Float16)b.z; o[7] = (_Float16)b.w;
  *reinterpret_cast<f16x8*>(out + base) = o;
}

// ---------------- conv + gating: y = Cg * causal_conv3(Bg * x) ----------------
__global__ __launch_bounds__(256) void conv_gate(const _Float16* __restrict__ BCx,
                                                 const float* __restrict__ Wc,   // [2048,1,3]
                                                 _Float16* __restrict__ Y) {
  const int h0 = threadIdx.x * 8;
  const int r0 = blockIdx.x * 8;
  const int s0 = r0 & 4095;

  float w0[8], w1[8], w2[8];
#pragma unroll
  for (int j = 0; j < 8; ++j) {
    w0[j] = Wc[(h0 + j) * 3 + 0];
    w1[j] = Wc[(h0 + j) * 3 + 1];
    w2[j] = Wc[(h0 + j) * 3 + 2];
  }

  float bxm2[8] = {}, bxm1[8] = {};
  if (s0 != 0) {
    const _Float16* pm2 = BCx + (size_t)(r0 - 2) * 6144 + h0;
    const _Float16* pm1 = BCx + (size_t)(r0 - 1) * 6144 + h0;
    f16x8 bg2 = *reinterpret_cast<const f16x8*>(pm2);
    f16x8 xx2 = *reinterpret_cast<const f16x8*>(pm2 + 4096);
    f16x8 bg1 = *reinterpret_cast<const f16x8*>(pm1);
    f16x8 xx1 = *reinterpret_cast<const f16x8*>(pm1 + 4096);
#pragma unroll
    for (int j = 0; j < 8; ++j) {
      bxm2[j] = (float)bg2[j] * (float)xx2[j];
      bxm1[j] = (float)bg1[j] * (float)xx1[j];
    }
  }

  for (int i = 0; i < 8; ++i) {
    const _Float16* pr = BCx + (size_t)(r0 + i) * 6144 + h0;
    f16x8 bg = *reinterpret_cast<const f16x8*>(pr);
    f16x8 cg = *reinterpret_cast<const f16x8*>(pr + 2048);
    f16x8 xx = *reinterpret_cast<const f16x8*>(pr + 4096);
    f16x8 o;
#pragma unroll
    for (int j = 0; j < 8; ++j) {
      float bx   = (float)bg[j] * (float)xx[j];
      float conv = w0[j] * bxm2[j] + w1[j] * bxm1[j] + w2[j] * bx;
      o[j] = (_Float16)((float)cg[j] * conv);
      bxm2[j] = bxm1[j];
      bxm1[j] = bx;
    }
    *reinterpret_cast<f16x8*>(Y + (size_t)(r0 + i) * 2048 + h0) = o;
  }
}

// ---------------- round-1 128x128 NT GEMM (proven) for out_proj ----------------
template <typename CT>
__global__ __launch_bounds__(256) void gemm_nt_f16(const _Float16* __restrict__ A,
                                                   const _Float16* __restrict__ B,
                                                   CT* __restrict__ C,
                                                   int M, int N, int K) {
  __shared__ _Float16 As[128 * 32];
  __shared__ _Float16 Bs[128 * 32];

  const int tid  = threadIdx.x;
  const int lane = tid & 63;
  const int wave = tid >> 6;
  const int wr   = wave >> 1;
  const int wc   = wave & 1;
  const int bm   = blockIdx.y * 128;
  const int bn   = blockIdx.x * 128;

  const _Float16* aS = A + (size_t)(bm + (tid >> 2)) * K + (tid & 3) * 8;
  const _Float16* bS = B + (size_t)(bn + (tid >> 2)) * K + (tid & 3) * 8;
  _Float16* sA = As + tid * 8;
  _Float16* sB = Bs + tid * 8;
  const size_t rowskip = (size_t)64 * K;

  f32x4 acc[4][4] = {};

  const int arow = wr * 64 + (lane & 15);
  const int brow = wc * 64 + (lane & 15);
  const int kofs = (lane >> 4) * 8;

  const int nk = K >> 5;
  for (int kt = 0; kt < nk; ++kt) {
    __syncthreads();
    GLD_LDS16(aS, sA);
    GLD_LDS16(aS + rowskip, sA + 2048);
    GLD_LDS16(bS, sB);
    GLD_LDS16(bS + rowskip, sB + 2048);
    aS += 32; bS += 32;
    __syncthreads();
    f16x8 af[4], bf[4];
#pragma unroll
    for (int f = 0; f < 4; ++f)
      af[f] = *reinterpret_cast<const f16x8*>(As + (arow + f * 16) * 32 + kofs);
#pragma unroll
    for (int f = 0; f < 4; ++f)
      bf[f] = *reinterpret_cast<const f16x8*>(Bs + (brow + f * 16) * 32 + kofs);
#pragma unroll
    for (int i = 0; i < 4; ++i)
#pragma unroll
      for (int j = 0; j < 4; ++j)
        acc[i][j] = __builtin_amdgcn_mfma_f32_16x16x32_f16(af[i], bf[j], acc[i][j], 0, 0, 0);
  }

  const int rbase = bm + wr * 64 + ((lane >> 4) << 2);
  const int cbase = bn + wc * 64 + (lane & 15);
#pragma unroll
  for (int i = 0; i < 4; ++i)
#pragma unroll
    for (int j = 0; j < 4; ++j) {
      const int r0 = rbase + i * 16;
      const int c  = cbase + j * 16;
#pragma unroll
      for (int reg = 0; reg < 4; ++reg)
        C[(size_t)(r0 + reg) * N + c] = (CT)acc[i][j][reg];
    }
}

// ---------------- 8-phase 256x256 NT GEMM (static 128KB LDS) ----------------
__device__ __forceinline__ void ldA(f16x8 (&af)[4][2], const _Float16* p, int base, int ak0, int ak1) {
#pragma unroll
  for (int i = 0; i < 4; ++i) {
    af[i][0] = *(const f16x8*)(p + base + i * 1024 + ak0);
    af[i][1] = *(const f16x8*)(p + base + i * 1024 + ak1);
  }
}
__device__ __forceinline__ void ldB(f16x8 (&bf)[2][2], const _Float16* p, int base, int ak0, int ak1) {
#pragma unroll
  for (int j = 0; j < 2; ++j) {
    bf[j][0] = *(const f16x8*)(p + base + j * 1024 + ak0);
    bf[j][1] = *(const f16x8*)(p + base + j * 1024 + ak1);
  }
}
template <int QM, int QN>
__device__ __forceinline__ void mfmaQ(f32x4 (&acc)[8][4], const f16x8 (&af)[4][2], const f16x8 (&bf)[2][2]) {
  __builtin_amdgcn_s_setprio(1);
#pragma unroll
  for (int i = 0; i < 4; ++i)
#pragma unroll
    for (int j = 0; j < 2; ++j)
#pragma unroll
      for (int ks = 0; ks < 2; ++ks)
        acc[QM * 4 + i][QN * 2 + j] =
            __builtin_amdgcn_mfma_f32_16x16x32_f16(af[i][ks], bf[j][ks], acc[QM * 4 + i][QN * 2 + j], 0, 0, 0);
  __builtin_amdgcn_s_setprio(0);
}

// A LDS: [256 rows][64 k] fp16, phys byte chunk ^= (row&7) (16B chunks)  [T2]
// B LDS: rows grouped so each 8KB staged unit is consumed by exactly one quadrant.
// Staging: gld_lds linear dest + inverse-swizzled per-lane SOURCE (rule 21).
__global__ __launch_bounds__(512, 2) void gemm8p(const _Float16* __restrict__ Ag,
                                                 const _Float16* __restrict__ Bg,
                                                 _Float16* __restrict__ Cg,
                                                 int N, int K, int nbn) {
  __shared__ __align__(16) char smem[131072];
  const int tid = threadIdx.x, lane = tid & 63, w = tid >> 6;
  const int wr = w >> 2, wc = w & 3;

  // T1: XCD-bijective block swizzle (grid % 8 == 0)
  const int nwg = (int)gridDim.x, q8 = nwg >> 3;
  const int swz = ((int)blockIdx.x & 7) * q8 + ((int)blockIdx.x >> 3);
  const int bm = (swz / nbn) << 8, bn = (swz % nbn) << 8;

  _Float16* const A0 = (_Float16*)(smem);
  _Float16* const B0 = (_Float16*)(smem + 32768);
  _Float16* const A1 = (_Float16*)(smem + 65536);
  _Float16* const B1 = (_Float16*)(smem + 98304);

  const int rr = tid >> 3;
  const int sCol = ((tid & 7) ^ (rr & 7)) * 8;                  // inverse-swizzled source chunk
  const _Float16* aSrc = Ag + (size_t)(bm + rr) * K + sCol;
  const _Float16* bSrc = Bg + (size_t)(bn + (rr >> 5) * 64 + (rr & 31)) * K + sCol;

  // read-side swizzle folds to per-lane constants (row&7 == lane&7 for all read rows)
  const int ak0 = ((lane >> 4) ^ (lane & 7)) * 8;
  const int ak1 = (((lane >> 4) + 4) ^ (lane & 7)) * 8;
  const int aRB = (wr * 128 + (lane & 15)) * 64;
  const int bRB = (wc * 32 + (lane & 15)) * 64;

  const int nt = K >> 6;

#define STG_A(NBO, kt, u) GLD_LDS16(aSrc + (size_t)(u) * 64 * K + (kt) * 64, \
                                    smem + (NBO) + (u) * 8192 + tid * 16)
#define STG_B(NBO, kt, u) GLD_LDS16(bSrc + (size_t)(((u) & 1) * 128 + ((u) >> 1) * 32) * K + (kt) * 64, \
                                    smem + (NBO) + 32768 + (u) * 8192 + tid * 16)

  f16x8 af[4][2], bf[2][2];
  f32x4 acc[8][4] = {};

  // prologue: tile 0 -> buffer 0, consumption order A0,A2,B0,B1 | B2,B3,A1,A3
  STG_A(0, 0, 0); STG_A(0, 0, 2);
  STG_B(0, 0, 0); STG_B(0, 0, 1);
  STG_B(0, 0, 2); STG_B(0, 0, 3);
  STG_A(0, 0, 1); STG_A(0, 0, 3);
  VMCNT4; BAR;

  // Per tile: 4 phases = C-quadrants (0,0),(0,1),(1,1),(1,0); stage slots consumption-
  // ordered so every wait is vmcnt(4): P0 stages A'{0,2}, P1 B'{0,1}, P2 B'{2,3}, P3 A'{1,3}.
#define TILE(AB, BB, NBO, t)                                       \
  {                                                                \
    const int tn = ((t) + 1 < nt) ? (t) + 1 : nt - 1;              \
    /* P0: q=(0,0) */                                              \
    ldA(af, AB, aRB, ak0, ak1);                                    \
    ldB(bf, BB, bRB, ak0, ak1);                                    \
    STG_A(NBO, tn, 0); STG_A(NBO, tn, 2);                          \
    BAR; LGKM0;                                                    \
    mfmaQ<0, 0>(acc, af, bf);                                      \
    VMCNT4; BAR;                                                   \
    /* P1: q=(0,1) */                                              \
    ldB(bf, BB, bRB + 8192, ak0, ak1);                             \
    STG_B(NBO, tn, 0); STG_B(NBO, tn, 1);                          \
    BAR; LGKM0;                                                    \
    mfmaQ<0, 1>(acc, af, bf);                                      \
    VMCNT4; BAR;                                                   \
    /* P2: q=(1,1) */                                              \
    ldA(af, AB, aRB + 4096, ak0, ak1);                             \
    STG_B(NBO, tn, 2); STG_B(NBO, tn, 3);                          \
    BAR; LGKM0;                                                    \
    mfmaQ<1, 1>(acc, af, bf);                                      \
    BAR;                                                           \
    /* P3: q=(1,0), re-read B half 0 */                            \
    ldB(bf, BB, bRB, ak0, ak1);                                    \
    STG_A(NBO, tn, 1); STG_A(NBO, tn, 3);                          \
    BAR; LGKM0;                                                    \
    mfmaQ<1, 0>(acc, af, bf);                                      \
    VMCNT4; BAR;                                                   \
  }

  for (int t = 0; t < nt; t += 2) {
    TILE(A0, B0, 65536, t);
    TILE(A1, B1, 0, t + 1);
  }
  VMCNT0;  // drain LDS-DMA (tail restage never consumed)

  const int rb = bm + wr * 128 + ((lane >> 4) << 2);
  const int cb = bn + wc * 64 + (lane & 15);
#pragma unroll
  for (int mi = 0; mi < 8; ++mi)
#pragma unroll
    for (int nj = 0; nj < 4; ++nj) {
      f32x4 v = acc[mi][nj];
#pragma unroll
      for (int rg = 0; rg < 4; ++rg)
        Cg[(size_t)(rb + mi * 16 + rg) * N + cb + nj * 16] = (_Float16)v[rg];
    }
#undef TILE
#undef STG_A
#undef STG_B
}

// ---------------- launcher ----------------
extern "C" void kernel_launch(void* const* d_in, const int* in_sizes, int n_in,
                              void* d_out, int out_size, void* d_ws, size_t ws_size,
                              hipStream_t stream) {
  const float* X  = (const float*)d_in[0];  // [2,4096,2048]
  const float* Wi = (const float*)d_in[1];  // [6144,2048]
  const float* Wc = (const float*)d_in[2];  // [2048,1,3]
  const float* Wo = (const float*)d_in[3];  // [2048,2048]
  float* out = (float*)d_out;               // [2,4096,2048] fp32

  char* ws = (char*)d_ws;
  _Float16* Xh   = (_Float16*)(ws);                    // 33,554,432 B
  _Float16* Wih  = (_Float16*)(ws + 33554432);         // 25,165,824 B
  _Float16* Woh  = (_Float16*)(ws + 58720256);         //  8,388,608 B
  _Float16* BCxh = (_Float16*)(ws + 67108864);         // 100,663,296 B
  _Float16* Yh   = (_Float16*)(ws + 167772160);        // 33,554,432 B
  (void)ws_size; (void)in_sizes; (void)n_in; (void)out_size;

  cvt_f32_f16<<<dim3(16777216 / 2048), 256, 0, stream>>>(X,  Xh,  16777216);
  cvt_f32_f16<<<dim3(12582912 / 2048), 256, 0, stream>>>(Wi, Wih, 12582912);
  cvt_f32_f16<<<dim3( 4194304 / 2048), 256, 0, stream>>>(Wo, Woh,  4194304);

  // in_proj: [8192,2048] x [6144,2048]^T -> BCx fp16   (32 x 24 = 768 blocks, 8-phase)
  gemm8p<<<dim3(768), 512, 0, stream>>>(Xh, Wih, BCxh, 6144, 2048, 24);

  conv_gate<<<dim3(1024), 256, 0, stream>>>(BCxh, Wc, Yh);

  // out_proj: [8192,2048] x [2048,2048]^T -> out fp32  (round-1 kernel, bisect control)
  gemm_nt_f16<float><<<dim3(16, 64), 256, 0, stream>>>(Yh, Woh, out, 8192, 2048, 2048);
}

// Round 5
// 314.090 us; speedup vs baseline: 1.3864x; 1.1108x over previous
//
#include <hip/hip_runtime.h>
#include <hip/hip_fp16.h>

// LFM2 short-conv block. Round 5: 256x256 8-phase GEMM for BOTH projections.
// Round-4 crash root cause: out_proj was launched with N=8192 (C stride) instead of
// N=2048 -> OOB C-writes. Fixed argument; kernel code identical to round-3's passing one.

typedef _Float16 f16x8 __attribute__((ext_vector_type(8)));
typedef float    f32x4 __attribute__((ext_vector_type(4)));

#define GLD_LDS16(gsrc, sdst) \
  __builtin_amdgcn_global_load_lds((const __attribute__((address_space(1))) void*)(gsrc), \
                                   (__attribute__((address_space(3))) void*)(sdst), 16, 0, 0)

#define VMCNT4 asm volatile("s_waitcnt vmcnt(4)" ::: "memory")
#define VMCNT0 asm volatile("s_waitcnt vmcnt(0)" ::: "memory")
#define LGKM0  asm volatile("s_waitcnt lgkmcnt(0)" ::: "memory")
#define BAR    __builtin_amdgcn_s_barrier()

// ---------------- fp32 -> fp16 convert (8 elems/thread) ----------------
__global__ __launch_bounds__(256) void cvt_f32_f16(const float* __restrict__ in,
                                                   _Float16* __restrict__ out, int n) {
  int i = blockIdx.x * 256 + threadIdx.x;
  int base = i * 8;
  if (base >= n) return;
  const float4* p = reinterpret_cast<const float4*>(in) + i * 2;
  float4 a = p[0], b = p[1];
  f16x8 o;
  o[0] = (_Float16)a.x; o[1] = (_Float16)a.y; o[2] = (_Float16)a.z; o[3] = (_Float16)a.w;
  o[4] = (_Float16)b.x; o[5] = (_Float16)b.y; o[6] = (_Float16)b.z; o[7] = (_Float16)b.w;
  *reinterpret_cast<f16x8*>(out + base) = o;
}

// ---------------- conv + gating: y = Cg * causal_conv3(Bg * x) ----------------
__global__ __launch_bounds__(256) void conv_gate(const _Float16* __restrict__ BCx,
                                                 const float* __restrict__ Wc,   // [2048,1,3]
                                                 _Float16* __restrict__ Y) {
  const int h0 = threadIdx.x * 8;
  const int r0 = blockIdx.x * 8;
  const int s0 = r0 & 4095;

  float w0[8], w1[8], w2[8];
#pragma unroll
  for (int j = 0; j < 8; ++j) {
    w0[j] = Wc[(h0 + j) * 3 + 0];
    w1[j] = Wc[(h0 + j) * 3 + 1];
    w2[j] = Wc[(h0 + j) * 3 + 2];
  }

  float bxm2[8] = {}, bxm1[8] = {};
  if (s0 != 0) {
    const _Float16* pm2 = BCx + (size_t)(r0 - 2) * 6144 + h0;
    const _Float16* pm1 = BCx + (size_t)(r0 - 1) * 6144 + h0;
    f16x8 bg2 = *reinterpret_cast<const f16x8*>(pm2);
    f16x8 xx2 = *reinterpret_cast<const f16x8*>(pm2 + 4096);
    f16x8 bg1 = *reinterpret_cast<const f16x8*>(pm1);
    f16x8 xx1 = *reinterpret_cast<const f16x8*>(pm1 + 4096);
#pragma unroll
    for (int j = 0; j < 8; ++j) {
      bxm2[j] = (float)bg2[j] * (float)xx2[j];
      bxm1[j] = (float)bg1[j] * (float)xx1[j];
    }
  }

  for (int i = 0; i < 8; ++i) {
    const _Float16* pr = BCx + (size_t)(r0 + i) * 6144 + h0;
    f16x8 bg = *reinterpret_cast<const f16x8*>(pr);
    f16x8 cg = *reinterpret_cast<const f16x8*>(pr + 2048);
    f16x8 xx = *reinterpret_cast<const f16x8*>(pr + 4096);
    f16x8 o;
#pragma unroll
    for (int j = 0; j < 8; ++j) {
      float bx   = (float)bg[j] * (float)xx[j];
      float conv = w0[j] * bxm2[j] + w1[j] * bxm1[j] + w2[j] * bx;
      o[j] = (_Float16)((float)cg[j] * conv);
      bxm2[j] = bxm1[j];
      bxm1[j] = bx;
    }
    *reinterpret_cast<f16x8*>(Y + (size_t)(r0 + i) * 2048 + h0) = o;
  }
}

// ---------------- 8-phase 256x256 NT GEMM (static 128KB LDS) ----------------
__device__ __forceinline__ void ldA(f16x8 (&af)[4][2], const _Float16* p, int base, int ak0, int ak1) {
#pragma unroll
  for (int i = 0; i < 4; ++i) {
    af[i][0] = *(const f16x8*)(p + base + i * 1024 + ak0);
    af[i][1] = *(const f16x8*)(p + base + i * 1024 + ak1);
  }
}
__device__ __forceinline__ void ldB(f16x8 (&bf)[2][2], const _Float16* p, int base, int ak0, int ak1) {
#pragma unroll
  for (int j = 0; j < 2; ++j) {
    bf[j][0] = *(const f16x8*)(p + base + j * 1024 + ak0);
    bf[j][1] = *(const f16x8*)(p + base + j * 1024 + ak1);
  }
}
template <int QM, int QN>
__device__ __forceinline__ void mfmaQ(f32x4 (&acc)[8][4], const f16x8 (&af)[4][2], const f16x8 (&bf)[2][2]) {
  __builtin_amdgcn_s_setprio(1);
#pragma unroll
  for (int i = 0; i < 4; ++i)
#pragma unroll
    for (int j = 0; j < 2; ++j)
#pragma unroll
      for (int ks = 0; ks < 2; ++ks)
        acc[QM * 4 + i][QN * 2 + j] =
            __builtin_amdgcn_mfma_f32_16x16x32_f16(af[i][ks], bf[j][ks], acc[QM * 4 + i][QN * 2 + j], 0, 0, 0);
  __builtin_amdgcn_s_setprio(0);
}

// A LDS: [256 rows][64 k] fp16, phys 16B-chunk ^= (row&7)  [T2 swizzle]
// B LDS: rows grouped so each 8KB staged unit is consumed by exactly one quadrant.
// Staging: gld_lds linear dest + inverse-swizzled per-lane SOURCE (rule 21).
// vmcnt ledger (per wave, FIFO): stage order per tile P0:A'{0,2} P1:B'{0,1} P2:B'{2,3}
// P3:A'{1,3}; vmcnt(4) at P0/P1/P3 end retires exactly the units the next phase reads;
// cross-wave visibility of retired DMA slices is guaranteed by the following s_barrier.
// ARGS: N = C column count/stride (output), K = reduction dim, nbn = N/256.
template <typename CT>
__global__ __launch_bounds__(512, 2) void gemm8p(const _Float16* __restrict__ Ag,
                                                 const _Float16* __restrict__ Bg,
                                                 CT* __restrict__ Cg,
                                                 int N, int K, int nbn) {
  __shared__ __align__(16) char smem[131072];
  const int tid = threadIdx.x, lane = tid & 63, w = tid >> 6;
  const int wr = w >> 2, wc = w & 3;

  // T1: XCD-bijective block swizzle (grid % 8 == 0)
  const int nwg = (int)gridDim.x, q8 = nwg >> 3;
  const int swz = ((int)blockIdx.x & 7) * q8 + ((int)blockIdx.x >> 3);
  const int bm = (swz / nbn) << 8, bn = (swz % nbn) << 8;

  _Float16* const A0 = (_Float16*)(smem);
  _Float16* const B0 = (_Float16*)(smem + 32768);
  _Float16* const A1 = (_Float16*)(smem + 65536);
  _Float16* const B1 = (_Float16*)(smem + 98304);

  const int rr = tid >> 3;
  const int sCol = ((tid & 7) ^ (rr & 7)) * 8;                  // inverse-swizzled source chunk
  const _Float16* aSrc = Ag + (size_t)(bm + rr) * K + sCol;
  const _Float16* bSrc = Bg + (size_t)(bn + (rr >> 5) * 64 + (rr & 31)) * K + sCol;

  // read-side swizzle folds to per-lane constants (row&7 == lane&7 for all read rows)
  const int ak0 = ((lane >> 4) ^ (lane & 7)) * 8;
  const int ak1 = (((lane >> 4) + 4) ^ (lane & 7)) * 8;
  const int aRB = (wr * 128 + (lane & 15)) * 64;
  const int bRB = (wc * 32 + (lane & 15)) * 64;

  const int nt = K >> 6;

#define STG_A(NBO, kt, u) GLD_LDS16(aSrc + (size_t)(u) * 64 * K + (kt) * 64, \
                                    smem + (NBO) + (u) * 8192 + tid * 16)
#define STG_B(NBO, kt, u) GLD_LDS16(bSrc + (size_t)(((u) & 1) * 128 + ((u) >> 1) * 32) * K + (kt) * 64, \
                                    smem + (NBO) + 32768 + (u) * 8192 + tid * 16)

  f16x8 af[4][2], bf[2][2];
  f32x4 acc[8][4] = {};

  // prologue: tile 0 -> buffer 0, consumption order A0,A2,B0,B1 | B2,B3,A1,A3
  STG_A(0, 0, 0); STG_A(0, 0, 2);
  STG_B(0, 0, 0); STG_B(0, 0, 1);
  STG_B(0, 0, 2); STG_B(0, 0, 3);
  STG_A(0, 0, 1); STG_A(0, 0, 3);
  VMCNT4; BAR;

  // Per tile: 4 phases = C-quadrants (0,0),(0,1),(1,1),(1,0); stage slots consumption-
  // ordered so every wait is vmcnt(4). Last tile restages tile nt-1 (harmless; keeps
  // the FIFO counts uniform so vmcnt(4) semantics hold on the final tile too).
#define TILE(AB, BB, NBO, t)                                       \
  {                                                                \
    const int tn = ((t) + 1 < nt) ? (t) + 1 : nt - 1;              \
    /* P0: q=(0,0) */                                              \
    ldA(af, AB, aRB, ak0, ak1);                                    \
    ldB(bf, BB, bRB, ak0, ak1);                                    \
    STG_A(NBO, tn, 0); STG_A(NBO, tn, 2);                          \
    BAR; LGKM0;                                                    \
    mfmaQ<0, 0>(acc, af, bf);                                      \
    VMCNT4; BAR;                                                   \
    /* P1: q=(0,1) */                                              \
    ldB(bf, BB, bRB + 8192, ak0, ak1);                             \
    STG_B(NBO, tn, 0); STG_B(NBO, tn, 1);                          \
    BAR; LGKM0;                                                    \
    mfmaQ<0, 1>(acc, af, bf);                                      \
    VMCNT4; BAR;                                                   \
    /* P2: q=(1,1) */                                              \
    ldA(af, AB, aRB + 4096, ak0, ak1);                             \
    STG_B(NBO, tn, 2); STG_B(NBO, tn, 3);                          \
    BAR; LGKM0;                                                    \
    mfmaQ<1, 1>(acc, af, bf);                                      \
    BAR;                                                           \
    /* P3: q=(1,0), re-read B half 0 */                            \
    ldB(bf, BB, bRB, ak0, ak1);                                    \
    STG_A(NBO, tn, 1); STG_A(NBO, tn, 3);                          \
    BAR; LGKM0;                                                    \
    mfmaQ<1, 0>(acc, af, bf);                                      \
    VMCNT4; BAR;                                                   \
  }

  for (int t = 0; t < nt; t += 2) {
    TILE(A0, B0, 65536, t);
    TILE(A1, B1, 0, t + 1);
  }
  VMCNT0;  // drain LDS-DMA (tail restage never consumed)

  const int rb = bm + wr * 128 + ((lane >> 4) << 2);
  const int cb = bn + wc * 64 + (lane & 15);
#pragma unroll
  for (int mi = 0; mi < 8; ++mi)
#pragma unroll
    for (int nj = 0; nj < 4; ++nj) {
      f32x4 v = acc[mi][nj];
#pragma unroll
      for (int rg = 0; rg < 4; ++rg)
        Cg[(size_t)(rb + mi * 16 + rg) * N + cb + nj * 16] = (CT)v[rg];
    }
#undef TILE
#undef STG_A
#undef STG_B
}

// ---------------- launcher ----------------
extern "C" void kernel_launch(void* const* d_in, const int* in_sizes, int n_in,
                              void* d_out, int out_size, void* d_ws, size_t ws_size,
                              hipStream_t stream) {
  const float* X  = (const float*)d_in[0];  // [2,4096,2048]
  const float* Wi = (const float*)d_in[1];  // [6144,2048]
  const float* Wc = (const float*)d_in[2];  // [2048,1,3]
  const float* Wo = (const float*)d_in[3];  // [2048,2048]
  float* out = (float*)d_out;               // [2,4096,2048] fp32

  char* ws = (char*)d_ws;
  _Float16* Xh   = (_Float16*)(ws);                    // 33,554,432 B
  _Float16* Wih  = (_Float16*)(ws + 33554432);         // 25,165,824 B
  _Float16* Woh  = (_Float16*)(ws + 58720256);         //  8,388,608 B
  _Float16* BCxh = (_Float16*)(ws + 67108864);         // 100,663,296 B
  _Float16* Yh   = (_Float16*)(ws + 167772160);        // 33,554,432 B
  (void)ws_size; (void)in_sizes; (void)n_in; (void)out_size;

  cvt_f32_f16<<<dim3(16777216 / 2048), 256, 0, stream>>>(X,  Xh,  16777216);
  cvt_f32_f16<<<dim3(12582912 / 2048), 256, 0, stream>>>(Wi, Wih, 12582912);
  cvt_f32_f16<<<dim3( 4194304 / 2048), 256, 0, stream>>>(Wo, Woh,  4194304);

  // in_proj: [8192,2048] x [6144,2048]^T -> BCx fp16   (32 x 24 = 768 blocks)
  gemm8p<_Float16><<<dim3(768), 512, 0, stream>>>(Xh, Wih, BCxh, 6144, 2048, 24);

  conv_gate<<<dim3(1024), 256, 0, stream>>>(BCxh, Wc, Yh);

  // out_proj: [8192,2048] x [2048,2048]^T -> out fp32  (32 x 8 = 256 blocks; N=2048!)
  gemm8p<float><<<dim3(256), 512, 0, stream>>>(Yh, Woh, out, 2048, 2048, 8);
}